// Round 1
// 342.331 us; speedup vs baseline: 1.0010x; 1.0010x over previous
//
#include <hip/hip_runtime.h>

#define BB 32
#define SS 4096
#define HH 512

typedef float f4 __attribute__((ext_vector_type(4)));   // native vec type:
// required by __builtin_nontemporal_load (HIP_vector_type float4 is rejected)

// ---------------------------------------------------------------------------
// Kernel 1: query[b,o] = sum_h dec[b,h] * W[o,h]
// 16-lane group per output element (4 outputs per wave). Each lane covers 32
// floats (8 x f4) of one W row; xor 1/2/4/8 reduce (single ds_swizzle each,
// 4-deep chain). W (1 MiB) + dec (64 KiB) are L2-resident; kernel is a few us.
// ---------------------------------------------------------------------------
__global__ __launch_bounds__(256) void query_kernel(const float* __restrict__ dec,
                                                    const float* __restrict__ W,
                                                    float* __restrict__ q) {
    const int wid  = (blockIdx.x * 256 + threadIdx.x) >> 6;  // 4096 waves
    const int lane = threadIdx.x & 63;
    const int l    = lane & 15;      // lane within group
    const int g    = lane >> 4;      // group 0..3 -> output o0+g
    const int b  = wid >> 7;         // 128 waves per batch (512 outputs / 4)
    const int o0 = (wid & 127) << 2; // 4 outputs per wave

    const f4* drow = (const f4*)(dec + (size_t)b * HH);
    const f4* wrow = (const f4*)(W + (size_t)(o0 + g) * HH);

    float s = 0.f;
    #pragma unroll
    for (int k = 0; k < 8; ++k) {
        f4 d = drow[l + 16 * k];
        f4 w = wrow[l + 16 * k];
        s += w.x * d.x + w.y * d.y + w.z * d.z + w.w * d.w;
    }
    s += __shfl_xor(s, 1, 64);
    s += __shfl_xor(s, 2, 64);
    s += __shfl_xor(s, 4, 64);
    s += __shfl_xor(s, 8, 64);

    if (l == 0) q[(size_t)b * HH + o0 + g] = s;
}

// ---------------------------------------------------------------------------
// Kernel 2: fused scores + context partials. Reads enc exactly ONCE (256 MiB).
//   score[b,s] = enc[b,s,:] . q[b,:]
//   partial[block,h] = sum_{s in block's 64 rows} score[b,s] * enc[b,s,h]
// 2048 blocks, 4 waves each. Each 16-lane group owns one row per set: lane
// holds 32 floats (8 x f4) of that row, so the score reduce is only 4 cheap
// xor<=8 shuffles (stays inside the group; no offset-32 bpermute in the hot
// loop). NO global atomics: each block writes one deterministic 2 KB partial
// to workspace; kernel 3 reduces. enc loads stay nontemporal (pure stream).
// ---------------------------------------------------------------------------
__global__ __launch_bounds__(256) void fused_kernel(const float* __restrict__ enc,
                                                    const float* __restrict__ q,
                                                    float* __restrict__ partial) {
    const int lane = threadIdx.x & 63;
    const int wave = threadIdx.x >> 6;
    const int l    = lane & 15;      // lane within group: h-slice selector
    const int g    = lane >> 4;      // group: row selector within a set
    const int b     = blockIdx.x >> 6;   // 64 blocks per batch
    const int chunk = blockIdx.x & 63;   // 64 chunks of 64 rows

    // q slices for this lane's h-columns (same for all 4 groups)
    const f4* q4 = (const f4*)(q + (size_t)b * HH);
    f4 qr[8];
    #pragma unroll
    for (int k = 0; k < 8; ++k) qr[k] = q4[l + 16 * k];

    f4 acc[8];
    #pragma unroll
    for (int k = 0; k < 8; ++k) acc[k] = {0.f, 0.f, 0.f, 0.f};

    const int rowBase = chunk * 64 + wave * 16;   // wave owns 16 contiguous rows
    const f4* encBase = (const f4*)(enc + ((size_t)b * SS + rowBase) * HH);

    for (int set = 0; set < 4; ++set) {
        // group g reads row (rowBase + set*4 + g); lane covers f4 cols l+16k
        const f4* rp = encBase + (size_t)(set * 4 + g) * 128;
        f4 e[8];
        #pragma unroll
        for (int k = 0; k < 8; ++k)
            e[k] = __builtin_nontemporal_load(rp + l + 16 * k);

        float dot = 0.f;
        #pragma unroll
        for (int k = 0; k < 8; ++k)
            dot += e[k].x * qr[k].x + e[k].y * qr[k].y
                 + e[k].z * qr[k].z + e[k].w * qr[k].w;

        // 16-lane reduce: all xor offsets <= 8 stay inside the group
        dot += __shfl_xor(dot, 1, 64);
        dot += __shfl_xor(dot, 2, 64);
        dot += __shfl_xor(dot, 4, 64);
        dot += __shfl_xor(dot, 8, 64);

        #pragma unroll
        for (int k = 0; k < 8; ++k) {
            acc[k].x += dot * e[k].x;
            acc[k].y += dot * e[k].y;
            acc[k].z += dot * e[k].z;
            acc[k].w += dot * e[k].w;
        }
    }

    // Cross-group combine: groups hold the SAME h-slices for different rows.
    // One xor16+xor32 butterfly per float, once per kernel.
    #pragma unroll
    for (int k = 0; k < 8; ++k) {
        acc[k].x += __shfl_xor(acc[k].x, 16, 64);
        acc[k].y += __shfl_xor(acc[k].y, 16, 64);
        acc[k].z += __shfl_xor(acc[k].z, 16, 64);
        acc[k].w += __shfl_xor(acc[k].w, 16, 64);
        acc[k].x += __shfl_xor(acc[k].x, 32, 64);
        acc[k].y += __shfl_xor(acc[k].y, 32, 64);
        acc[k].z += __shfl_xor(acc[k].z, 32, 64);
        acc[k].w += __shfl_xor(acc[k].w, 32, 64);
    }

    // Cross-wave combine in LDS (8 KiB), then ONE coalesced partial write.
    __shared__ f4 cbuf[4][128];
    if (g == 0) {
        #pragma unroll
        for (int k = 0; k < 8; ++k) cbuf[wave][l + 16 * k] = acc[k];
    }
    __syncthreads();

    if (threadIdx.x < 128) {
        f4 v = cbuf[0][threadIdx.x] + cbuf[1][threadIdx.x]
             + cbuf[2][threadIdx.x] + cbuf[3][threadIdx.x];
        ((f4*)(partial + (size_t)blockIdx.x * HH))[threadIdx.x] = v;
    }
}

// ---------------------------------------------------------------------------
// Kernel 3: out[b,h] = sum over the batch's 64 chunk-partials. 4 MB read,
// deterministic single write of every output element (no zero-init needed).
// ---------------------------------------------------------------------------
__global__ __launch_bounds__(128) void reduce_kernel(const f4* __restrict__ partial,
                                                     f4* __restrict__ out) {
    const int b = blockIdx.x;        // 32 blocks
    const int t = threadIdx.x;       // f4 column 0..127
    const f4* p = partial + (size_t)b * 64 * 128 + t;

    f4 v0 = {0.f, 0.f, 0.f, 0.f}, v1 = v0, v2 = v0, v3 = v0;
    #pragma unroll 4
    for (int j = 0; j < 64; j += 4) {
        v0 += p[(size_t)(j + 0) * 128];
        v1 += p[(size_t)(j + 1) * 128];
        v2 += p[(size_t)(j + 2) * 128];
        v3 += p[(size_t)(j + 3) * 128];
    }
    out[(size_t)b * 128 + t] = (v0 + v1) + (v2 + v3);
}

extern "C" void kernel_launch(void* const* d_in, const int* in_sizes, int n_in,
                              void* d_out, int out_size, void* d_ws, size_t ws_size,
                              hipStream_t stream) {
    const float* enc = (const float*)d_in[0];  // [B, S, H]
    const float* dec = (const float*)d_in[1];  // [B, 1, H]
    const float* W   = (const float*)d_in[2];  // [H, H]
    float* out = (float*)d_out;                // [B, 1, H] fp32
    float* q       = (float*)d_ws;             // [B, H] scratch (64 KiB)
    float* partial = (float*)d_ws + BB * HH;   // [2048, H] scratch (4 MiB)

    // No memset: out is written exactly once by reduce_kernel (no atomics).

    // 16384 outputs, 4 per wave, 4 waves/block -> 1024 blocks
    query_kernel<<<dim3(1024), dim3(256), 0, stream>>>(dec, W, q);

    // 32 batches x 64 chunks = 2048 blocks
    fused_kernel<<<dim3(2048), dim3(256), 0, stream>>>(enc, q, partial);

    // one block per batch
    reduce_kernel<<<dim3(32), dim3(128), 0, stream>>>((const f4*)partial, (f4*)out);
}